// Round 8
// baseline (1898.911 us; speedup 1.0000x reference)
//
#include <hip/hip_runtime.h>
#include <math.h>

#define BB 128
#define T2 2050
#define TT 2049
#define HH 64
#define GG 448   // 7*H
#define KK 100
#define NE 103   // K+3
#define NSTAGE 2056  // staged ev/dt length (TT + pipeline pad)
#define NTHREADS 384 // 6 waves: 4 gate + 2 logit

#define LOG2E 1.44269504088896340736f
#define LN2   0.69314718055994530942f

// ---- fast transcendentals (native v_exp_f32 / v_log_f32 / v_rcp_f32) ----
__device__ __forceinline__ float frcp(float x) { return __builtin_amdgcn_rcpf(x); }

__device__ __forceinline__ float sigmoid_fast(float x) {
    return frcp(1.f + exp2f(-x * LOG2E));
}
__device__ __forceinline__ float tanh_fast(float x) {
    float e = exp2f(x * (2.f * LOG2E));
    return 1.f - 2.f * frcp(1.f + e);
}
__device__ __forceinline__ float softplus_fast(float x) {
    float t = exp2f(-fabsf(x) * LOG2E);
    return fmaxf(x, 0.f) + LN2 * log2f(1.f + t);
}

// Sum over the 4 k4 row-groups (16-lane rows) using gfx950 VALU permlane
// swaps — NO DS-pipe traffic (the R6 bottleneck). With a=b=v:
//   permlane16_swap: a'=[r0,r0,r2,r2], b'=[r1,r1,r3,r3] -> a'+b' = row-pair sums
//   permlane32_swap on s: x'=[s01*4], y'=[s23*4]         -> x'+y' = total, all lanes
__device__ __forceinline__ float ksum4(float v) {
    float a = v, b = v;
    asm("v_permlane16_swap_b32 %0, %1" : "+v"(a), "+v"(b));
    float s = a + b;
    float x = s, y = s;
    asm("v_permlane32_swap_b32 %0, %1" : "+v"(x), "+v"(y));
    return x + y;
}

// pre_emb[e][t] = sum_k in_emb[e][k] * Wx[k][t] + bias[t]   (103 x 448)
__global__ void pre_emb_kernel(const float* __restrict__ in_emb,
                               const float* __restrict__ Wx,
                               const float* __restrict__ bias,
                               float* __restrict__ pre_emb) {
    int e = blockIdx.x;
    int t = threadIdx.x;
    float acc = bias[t];
#pragma unroll
    for (int k = 0; k < HH; ++k)
        acc = fmaf(in_emb[e * HH + k], Wx[k * GG + t], acc);
    pre_emb[e * GG + t] = acc;
}

// Raw barrier: fence LDS only (lgkmcnt); global loads/stores stay in flight.
__device__ __forceinline__ void step_barrier() {
    __builtin_amdgcn_sched_barrier(0);
    asm volatile("s_waitcnt lgkmcnt(0)" ::: "memory");
    __builtin_amdgcn_s_barrier();
    __builtin_amdgcn_sched_barrier(0);
}

// One block per batch row; 6 waves (4 gate + 2 logit), ONE lgkm barrier/step.
//  - gate wave w owns elements [16w,16w+16); lane (k4=l>>4, c16=l&15) holds
//    Wh[k-slice 16k4..+16][7 gates of element 16w+c16] = 112 pinned VGPRs.
//    Per step it reads ONLY its k-slice of h (4 ds_read_b128), does 112 fmaf,
//    reduces over k4 with VALU permlane swaps, adds pre, applies activations
//    and the state update (redundant across k4 groups), and lanes k4==0
//    publish h. Gates are produced and consumed IN-WAVE: no gate exchange.
//  - logit waves (w=4,5) own 50 out_emb cols each (4 col-slots x 16 k),
//    same k-split/reduce, softplus, store rows straight to out (1 step
//    behind), fire-and-forget behind the lgkm-only barrier.
//  Per-step LDS: ~30 instrs (vs 112 in the 1347us R6) — the measured bound.
__launch_bounds__(NTHREADS, 1)
__global__ void scan_kernel(const int* __restrict__ event,
                            const float* __restrict__ dtime,
                            const float* __restrict__ pre_emb,
                            const float* __restrict__ Wh,
                            const float* __restrict__ oe,
                            float* __restrict__ out) {
    const int b   = blockIdx.x;
    const int tid = threadIdx.x;
    const int w   = tid >> 6;     // wave 0..5
    const int l   = tid & 63;     // lane
    const int k4  = l >> 4;       // k-group 0..3 (16-lane row)
    const int c16 = l & 15;       // column slot 0..15

    __shared__ __align__(16) float hs[2][HH];   // double-buffered h
    __shared__ int   evoff_s[NSTAGE];           // pre_emb row offsets
    __shared__ float dtl_s[NSTAGE];

    const bool is_gate = (w < 4);
    const int  jw      = w - 4;                 // logit wave index 0..1
    const int  colb    = 16 * (w & 3) + c16;    // gate: owned element

    const int*   ev_row  = event + b * T2;
    const float* dt_row  = dtime + b * T2;
    float*       out_row = out + (size_t)b * TT * KK;

    // ---- stage ev (as row offsets) and dt into LDS (one-time) ----
    for (int i = tid; i < NSTAGE; i += NTHREADS) {
        const int idx = (i < T2) ? i : (T2 - 1);
        evoff_s[i] = ev_row[idx] * GG;
        dtl_s[i]   = dt_row[idx];
    }

    // ---- register-resident weights (pinned: no remat/spill, cf. R7) ----
    float wg[7][16];   // gate: Wh[16k4+kk][g*64 + colb]
    float wl[4][16];   // logit: oe[col][16k4+kk]
    if (is_gate) {
#pragma unroll
        for (int g = 0; g < 7; ++g)
#pragma unroll
            for (int kk = 0; kk < 16; ++kk)
                wg[g][kk] = Wh[(16 * k4 + kk) * GG + g * 64 + colb];
#pragma unroll
        for (int g = 0; g < 7; ++g)
#pragma unroll
            for (int kk = 0; kk < 16; ++kk)
                asm volatile("" : "+v"(wg[g][kk]));
    } else {
#pragma unroll
        for (int j = 0; j < 4; ++j) {
            const bool valid = (c16 + 16 * j) < 50;
            const int  col   = valid ? (50 * jw + c16 + 16 * j) : (50 * jw);
#pragma unroll
            for (int kk = 0; kk < 16; ++kk)
                wl[j][kk] = oe[col * HH + 16 * k4 + kk];
        }
#pragma unroll
        for (int j = 0; j < 4; ++j)
#pragma unroll
            for (int kk = 0; kk < 16; ++kk)
                asm volatile("" : "+v"(wl[j][kk]));
    }

    if (tid < HH) hs[0][tid] = 0.f;
    __syncthreads();   // evoff_s/dtl_s/hs[0] ready

    // ---- gate prologue: 2-step-deep pre/dt pipelines (parity regs) ----
    float preE[7], preO[7];
    int   offE = 0, offO = 0;
    float dtE = 0.f, dtO = 0.f;
    if (is_gate) {
        const int o0 = evoff_s[0], o1 = evoff_s[1];
#pragma unroll
        for (int g = 0; g < 7; ++g) {
            preE[g] = pre_emb[o0 + g * 64 + colb];   // pre_0
            preO[g] = pre_emb[o1 + g * 64 + colb];   // pre_1
        }
        offE = evoff_s[2];
        offO = evoff_s[3];
        dtE  = dtl_s[1];     // step t uses dt = dtime[t+1]
        dtO  = dtl_s[2];
    }

    float c = 0.f, cb = 0.f;

    // logit store bookkeeping
    const int  lc0 = 50 * jw + c16;
    const int  lc1 = lc0 + 16;
    const int  lc2 = lc0 + 32;
    const int  lc3 = lc0 + 48;      // valid only for c16 < 2
    float*     outP = out_row;

// ---- gate step t: h_{t-1} in hs[RB]; writes h_t to hs[WB] ----
#define GATE_STEP(RB, WB, PRE, OFF, DTV, TIDX)                                  \
    {                                                                           \
        float pu[7];                                                            \
        _Pragma("unroll") for (int g = 0; g < 7; ++g) pu[g] = PRE[g];           \
        const float* pb = pre_emb + OFF;                                        \
        _Pragma("unroll") for (int g = 0; g < 7; ++g) PRE[g] = pb[g * 64 + colb]; \
        OFF = evoff_s[(TIDX) + 4];                                              \
        const float dtu = DTV;                                                  \
        DTV = dtl_s[(TIDX) + 3];                                                \
        const float4* hp = (const float4*)&hs[RB][16 * k4];                     \
        const float4 hv0 = hp[0], hv1 = hp[1], hv2 = hp[2], hv3 = hp[3];        \
        float acc[7];                                                           \
        _Pragma("unroll") for (int g = 0; g < 7; ++g) {                         \
            float a = hv0.x * wg[g][0];                                         \
            a = fmaf(hv0.y, wg[g][1],  a);                                      \
            a = fmaf(hv0.z, wg[g][2],  a);                                      \
            a = fmaf(hv0.w, wg[g][3],  a);                                      \
            a = fmaf(hv1.x, wg[g][4],  a);                                      \
            a = fmaf(hv1.y, wg[g][5],  a);                                      \
            a = fmaf(hv1.z, wg[g][6],  a);                                      \
            a = fmaf(hv1.w, wg[g][7],  a);                                      \
            a = fmaf(hv2.x, wg[g][8],  a);                                      \
            a = fmaf(hv2.y, wg[g][9],  a);                                      \
            a = fmaf(hv2.z, wg[g][10], a);                                      \
            a = fmaf(hv2.w, wg[g][11], a);                                      \
            a = fmaf(hv3.x, wg[g][12], a);                                      \
            a = fmaf(hv3.y, wg[g][13], a);                                      \
            a = fmaf(hv3.z, wg[g][14], a);                                      \
            a = fmaf(hv3.w, wg[g][15], a);                                      \
            acc[g] = a;                                                         \
        }                                                                       \
        float gate[7];                                                          \
        _Pragma("unroll") for (int g = 0; g < 7; ++g)                           \
            gate[g] = ksum4(acc[g]) + pu[g];                                    \
        const float ed  = exp2f(-dtu * log2f(1.f + exp2f(gate[6] * LOG2E)));    \
        const float zg  = tanh_fast(gate[2]);                                   \
        const float ig  = sigmoid_fast(gate[0]);                                \
        const float fg  = sigmoid_fast(gate[1]);                                \
        const float ibg = sigmoid_fast(gate[4]);                                \
        const float fbg = sigmoid_fast(gate[5]);                                \
        const float og  = sigmoid_fast(gate[3]);                                \
        const float ci  = fmaf(fg, c, ig * zg);                                 \
        const float cbi = fmaf(fbg, cb, ibg * zg);                              \
        const float cn  = fmaf(ci - cbi, ed, cbi);                              \
        const float h   = og * tanh_fast(cn);                                   \
        c  = cn;                                                                \
        cb = cbi;                                                               \
        if (k4 == 0) hs[WB][colb] = h;                                          \
    }

// ---- logit step: logits of h in hs[RB] -> row (outP); 1 step behind ----
#define LOGIT_STEP(RB, DO_STORE)                                                \
    {                                                                           \
        const float4* hp = (const float4*)&hs[RB][16 * k4];                     \
        const float4 hv0 = hp[0], hv1 = hp[1], hv2 = hp[2], hv3 = hp[3];        \
        float acc[4];                                                           \
        _Pragma("unroll") for (int j = 0; j < 4; ++j) {                         \
            float a = hv0.x * wl[j][0];                                         \
            a = fmaf(hv0.y, wl[j][1],  a);                                      \
            a = fmaf(hv0.z, wl[j][2],  a);                                      \
            a = fmaf(hv0.w, wl[j][3],  a);                                      \
            a = fmaf(hv1.x, wl[j][4],  a);                                      \
            a = fmaf(hv1.y, wl[j][5],  a);                                      \
            a = fmaf(hv1.z, wl[j][6],  a);                                      \
            a = fmaf(hv1.w, wl[j][7],  a);                                      \
            a = fmaf(hv2.x, wl[j][8],  a);                                      \
            a = fmaf(hv2.y, wl[j][9],  a);                                      \
            a = fmaf(hv2.z, wl[j][10], a);                                      \
            a = fmaf(hv2.w, wl[j][11], a);                                      \
            a = fmaf(hv3.x, wl[j][12], a);                                      \
            a = fmaf(hv3.y, wl[j][13], a);                                      \
            a = fmaf(hv3.z, wl[j][14], a);                                      \
            a = fmaf(hv3.w, wl[j][15], a);                                      \
            acc[j] = a;                                                         \
        }                                                                       \
        const float r0 = ksum4(acc[0]);                                         \
        const float r1 = ksum4(acc[1]);                                         \
        const float r2 = ksum4(acc[2]);                                         \
        const float r3 = ksum4(acc[3]);                                         \
        if (DO_STORE) {                                                         \
            if (k4 == 0) {                                                      \
                outP[lc0] = softplus_fast(r0);                                  \
                outP[lc1] = softplus_fast(r1);                                  \
                outP[lc2] = softplus_fast(r2);                                  \
                if (c16 < 2) outP[lc3] = softplus_fast(r3);                     \
            }                                                                   \
            outP += KK;                                                         \
        }                                                                       \
    }

    // main loop: 1024 double-steps cover t = 0..2047
    for (int tp = 0; tp < (TT - 1) / 2; ++tp) {
        const int te = 2 * tp;
        if (is_gate) { GATE_STEP(0, 1, preE, offE, dtE, te) }
        else         { LOGIT_STEP(0, (te > 0)) }      // h_{t-1}, t even
        step_barrier();
        if (is_gate) { GATE_STEP(1, 0, preO, offO, dtO, te + 1) }
        else         { LOGIT_STEP(1, true) }          // h_{t-1}, t odd
        step_barrier();
    }
    // tail step t = 2048 (even: read hs[0], write hs[1])
    if (is_gate) { GATE_STEP(0, 1, preE, offE, dtE, TT - 1) }
    else         { LOGIT_STEP(0, true) }
    step_barrier();

    // final logits: h_{2048} in hs[1] -> row 2048
    if (!is_gate) { LOGIT_STEP(1, true) }

#undef GATE_STEP
#undef LOGIT_STEP
}

extern "C" void kernel_launch(void* const* d_in, const int* in_sizes, int n_in,
                              void* d_out, int out_size, void* d_ws, size_t ws_size,
                              hipStream_t stream) {
    const int*   event  = (const int*)d_in[0];
    const float* dtime  = (const float*)d_in[1];
    const float* in_emb = (const float*)d_in[2];
    const float* Wx     = (const float*)d_in[3];
    const float* Wh     = (const float*)d_in[4];
    const float* bias   = (const float*)d_in[5];
    const float* oe     = (const float*)d_in[6];
    float*       out    = (float*)d_out;

    float* pre_emb = (float*)d_ws;  // 103*448*4 = 184,576 bytes

    pre_emb_kernel<<<NE, GG, 0, stream>>>(in_emb, Wx, bias, pre_emb);
    scan_kernel<<<BB, NTHREADS, 0, stream>>>(event, dtime, pre_emb, Wh, oe, out);
}